// Round 5
// baseline (757.244 us; speedup 1.0000x reference)
//
#include <hip/hip_runtime.h>
#include <stdint.h>
#include <stdio.h>

#define BB   16
#define LL   512
#define CC   384
#define FF   384
#define KW   3
#define MEL  4096
#define KKT  (CC*KW)   // 1152

// output section offsets (fp32 elements)
#define O_OUT 0
#define N_OUT (BB*MEL*CC)          // 25165824
#define O_DUR (N_OUT)
#define O_PIT (O_DUR + BB*LL)
#define O_EN  (O_PIT + BB*MEL)

using bf16x8 = __attribute__((ext_vector_type(8))) short;
using f32x4  = __attribute__((ext_vector_type(4))) float;

__device__ __forceinline__ unsigned short f2bf(float v) {
    union { float f; unsigned int u; } cv; cv.f = v;
    unsigned int u = cv.u;
    u += 0x7FFFu + ((u >> 16) & 1u);   // RNE
    return (unsigned short)(u >> 16);
}
__device__ __forceinline__ float bf2f(unsigned short u) {
    union { unsigned int u; float f; } cv; cv.u = ((unsigned int)u) << 16; return cv.f;
}

__device__ __forceinline__ void gld_lds16(const unsigned short* gp, unsigned short* lp) {
    __builtin_amdgcn_global_load_lds(
        (const __attribute__((address_space(1))) unsigned int*)gp,
        (__attribute__((address_space(3))) unsigned int*)lp, 16, 0, 0);
}

// ---------------- weight transform: w[F][C][K] fp32 -> wt[F][k*C+c] bf16 ----
__global__ void wtrans_kernel(const float* __restrict__ w, unsigned short* __restrict__ wt) {
    int i = blockIdx.x * 256 + threadIdx.x;
    if (i >= FF * KKT) return;
    int f = i / KKT;
    int r = i - f * KKT;
    int k = r / CC;
    int c = r - k * CC;
    wt[i] = f2bf(w[(size_t)f * KKT + c * KW + k]);
}

// ---------------- x fp32 -> padded bf16 [B][L+2][C] ------------------------
__global__ void convert_x_kernel(const float* __restrict__ x, unsigned short* __restrict__ o) {
    int i = blockIdx.x * 256 + threadIdx.x;
    if (i >= BB * LL * CC) return;
    int b = i / (LL * CC);
    int r = i - b * (LL * CC);
    int t = r / CC;
    int c = r - t * CC;
    o[((size_t)b * (LL + 2) + t + 1) * CC + c] = f2bf(x[i]);
}

// ---------------- zero the two pad rows per batch --------------------------
__global__ void zpad_kernel(unsigned short* __restrict__ buf, int T) {
    int b = blockIdx.x >> 1;
    int w = blockIdx.x & 1;
    size_t row = (size_t)b * (T + 2) + (w ? (T + 1) : 0);
    buf[row * CC + threadIdx.x] = 0;
}

// ---------------- fused Conv(K=3)+bias+ReLU+LN [+Linear] -------------------
// Tile M=128 x N=384(all F). 512 thr, 8 waves (2M x 4N), per-wave 64x96.
// 4-buffer circular LDS, depth-3 prefetch, counted vmcnt(8), 1 barrier/step.
// LDS layout is k-chunk-major: A[(q*128+row)*8], B[(q*384+col)*8] (16B cells)
// -> fragment ds_read_b128 is bank-conflict-free by construction.
template<int T, bool FL>
__global__ __launch_bounds__(512)
void conv_ln_kernel(const unsigned short* __restrict__ inb,
                    const unsigned short* __restrict__ wt,
                    const float* __restrict__ bias,
                    const float* __restrict__ g,
                    const float* __restrict__ be,
                    unsigned short* __restrict__ outb,
                    const float* __restrict__ wl,
                    const float* __restrict__ bl,
                    float* __restrict__ op) {
    // per buffer: A 128x32 (4096 shorts, 8KB) + B 384x32 (12288 shorts, 24KB)
    __shared__ __align__(16) unsigned short LDS[4][16384];

    constexpr int NT = KKT / 32;   // 36
    const int m0 = blockIdx.x * 128;
    const int b  = m0 / T;
    const int t0 = m0 - b * T;
    const int tid  = threadIdx.x;
    const int lane = tid & 63;
    const int wv   = tid >> 6;
    const int wr   = wv >> 2;          // 0..1 -> 64 rows
    const int wc   = wv & 3;           // 0..3 -> 96 cols

    // staging sources, chunk-major: A chunk cidx=tid -> (q=tid>>7, r=tid&127)
    const unsigned short* srcA =
        inb + ((size_t)b * (T + 2) + t0 + (tid & 127)) * CC + (tid >> 7) * 8;
    // B chunk cidx = s*512+tid -> (q=cidx/384, bn=cidx%384)
    const unsigned short* srcB0, *srcB1, *srcB2;
    {
        int cidx = tid;        int q = cidx / 384, bn = cidx - q * 384;
        srcB0 = wt + (size_t)bn * KKT + q * 8;
        cidx = 512 + tid;      q = cidx / 384; bn = cidx - q * 384;
        srcB1 = wt + (size_t)bn * KKT + q * 8;
        cidx = 1024 + tid;     q = cidx / 384; bn = cidx - q * 384;
        srcB2 = wt + (size_t)bn * KKT + q * 8;
    }

    f32x4 acc[4][6] = {};

    auto stage = [&](int bi, int t) {
        const int off = t * 32;    // A & B addrs advance 32 shorts per K-step
        gld_lds16(srcA  + off, &LDS[bi][wv * 512]);
        gld_lds16(srcB0 + off, &LDS[bi][4096 + 0 * 4096 + wv * 512]);
        gld_lds16(srcB1 + off, &LDS[bi][4096 + 1 * 4096 + wv * 512]);
        gld_lds16(srcB2 + off, &LDS[bi][4096 + 2 * 4096 + wv * 512]);
    };

    auto compute = [&](int bi) {
        bf16x8 af[4], bf[6];
        const int q = lane >> 4;
        #pragma unroll
        for (int i = 0; i < 4; ++i) {
            const int ar = wr * 64 + i * 16 + (lane & 15);
            af[i] = *reinterpret_cast<const bf16x8*>(&LDS[bi][(q * 128 + ar) * 8]);
        }
        #pragma unroll
        for (int j = 0; j < 6; ++j) {
            const int bn = wc * 96 + j * 16 + (lane & 15);
            bf[j] = *reinterpret_cast<const bf16x8*>(&LDS[bi][4096 + (q * 384 + bn) * 8]);
        }
        __builtin_amdgcn_s_setprio(1);
        #pragma unroll
        for (int i = 0; i < 4; ++i)
            #pragma unroll
            for (int j = 0; j < 6; ++j)
                acc[i][j] = __builtin_amdgcn_mfma_f32_16x16x32_bf16(
                    af[i], bf[j], acc[i][j], 0, 0, 0);
        __builtin_amdgcn_s_setprio(0);
    };

    // depth-3 prologue
    stage(0, 0);
    stage(1, 1);
    stage(2, 2);

    #pragma unroll 4
    for (int t = 0; t < NT; ++t) {
        // my stage for tile t (issued 3 steps ago) has landed when <=8 remain
        asm volatile("s_waitcnt vmcnt(8)" ::: "memory");
        __builtin_amdgcn_s_barrier();     // everyone's tile-t loads landed;
        asm volatile("" ::: "memory");    // everyone's t-1 reads consumed
        int nt_ = t + 3; if (nt_ > NT - 1) nt_ = NT - 1;   // clamped dup-stage tail
        stage((t + 3) & 3, nt_);
        asm volatile("" ::: "memory");
        compute(t & 3);
    }
    asm volatile("s_waitcnt vmcnt(0)" ::: "memory");  // drain dup stages
    __syncthreads();

    // ---------------- epilogue: bias + ReLU + LN [+ Linear] ----------------
    const int colb = wc * 96 + (lane & 15);
    float b6[6];
    #pragma unroll
    for (int j = 0; j < 6; ++j) b6[j] = bias[colb + j * 16];
    #pragma unroll
    for (int i = 0; i < 4; ++i)
        #pragma unroll
        for (int j = 0; j < 6; ++j)
            #pragma unroll
            for (int r = 0; r < 4; ++r) {
                float v = acc[i][j][r] + b6[j];
                acc[i][j][r] = v > 0.f ? v : 0.f;
            }

    // per-row partial sums (16-lane groups share a row)
    float S1[4][4], S2[4][4];
    #pragma unroll
    for (int i = 0; i < 4; ++i)
        #pragma unroll
        for (int r = 0; r < 4; ++r) {
            float s = 0.f, s2 = 0.f;
            #pragma unroll
            for (int j = 0; j < 6; ++j) { const float v = acc[i][j][r]; s += v; s2 += v * v; }
            #pragma unroll
            for (int m = 1; m <= 8; m <<= 1) { s += __shfl_xor(s, m); s2 += __shfl_xor(s2, m); }
            S1[i][r] = s; S2[i][r] = s2;
        }

    float2* red = (float2*)&LDS[0][0];     // 128 rows x 4 col-waves
    if ((lane & 15) == 0) {
        const int q = lane >> 4;
        #pragma unroll
        for (int i = 0; i < 4; ++i)
            #pragma unroll
            for (int r = 0; r < 4; ++r)
                red[(wr * 64 + i * 16 + q * 4 + r) * 4 + wc] = make_float2(S1[i][r], S2[i][r]);
    }
    __syncthreads();

    float g6[6], be6[6];
    #pragma unroll
    for (int j = 0; j < 6; ++j) { g6[j] = g[colb + j * 16]; be6[j] = be[colb + j * 16]; }

    if (!FL) {
        #pragma unroll
        for (int i = 0; i < 4; ++i)
            #pragma unroll
            for (int r = 0; r < 4; ++r) {
                const int row = wr * 64 + i * 16 + (lane >> 4) * 4 + r;
                const float2 p0 = red[row * 4 + 0], p1 = red[row * 4 + 1];
                const float2 p2 = red[row * 4 + 2], p3 = red[row * 4 + 3];
                const float S = p0.x + p1.x + p2.x + p3.x;
                const float Q = p0.y + p1.y + p2.y + p3.y;
                const float mu = S * (1.f / 384.f);
                const float rs = rsqrtf(Q * (1.f / 384.f) - mu * mu + 1e-5f);
                unsigned short* qp = outb + ((size_t)b * (T + 2) + t0 + row + 1) * CC + colb;
                #pragma unroll
                for (int j = 0; j < 6; ++j)
                    qp[j * 16] = f2bf((acc[i][j][r] - mu) * rs * g6[j] + be6[j]);
            }
    } else {
        float wl6[6];
        #pragma unroll
        for (int j = 0; j < 6; ++j) wl6[j] = wl[colb + j * 16];
        float* redl = (float*)&LDS[1][0];
        #pragma unroll
        for (int i = 0; i < 4; ++i)
            #pragma unroll
            for (int r = 0; r < 4; ++r) {
                const int row = wr * 64 + i * 16 + (lane >> 4) * 4 + r;
                const float2 p0 = red[row * 4 + 0], p1 = red[row * 4 + 1];
                const float2 p2 = red[row * 4 + 2], p3 = red[row * 4 + 3];
                const float S = p0.x + p1.x + p2.x + p3.x;
                const float Q = p0.y + p1.y + p2.y + p3.y;
                const float mu = S * (1.f / 384.f);
                const float rs = rsqrtf(Q * (1.f / 384.f) - mu * mu + 1e-5f);
                float sl = 0.f;
                #pragma unroll
                for (int j = 0; j < 6; ++j)
                    sl += ((acc[i][j][r] - mu) * rs * g6[j] + be6[j]) * wl6[j];
                #pragma unroll
                for (int m = 1; m <= 8; m <<= 1) sl += __shfl_xor(sl, m);
                if ((lane & 15) == 0) redl[row * 4 + wc] = sl;
            }
        __syncthreads();
        if (tid < 128)
            op[m0 + tid] = redl[tid * 4] + redl[tid * 4 + 1] +
                           redl[tid * 4 + 2] + redl[tid * 4 + 3] + bl[0];
    }
}

// ---------------- cumsum of dur per batch ----------------------------------
__global__ void cumsum_kernel(const int* __restrict__ dur, int* __restrict__ cum) {
    __shared__ int s[LL];
    const int b = blockIdx.x, t = threadIdx.x;
    s[t] = dur[b * LL + t];
    __syncthreads();
    for (int off = 1; off < LL; off <<= 1) {
        int v = (t >= off) ? s[t - off] : 0;
        __syncthreads();
        s[t] += v;
        __syncthreads();
    }
    cum[b * LL + t] = s[t];
}

// ---------------- frame -> phoneme index (binary search), -1 if masked -----
__global__ void idx_kernel(const int* __restrict__ cum, int* __restrict__ idxm) {
    const int i = blockIdx.x * 256 + threadIdx.x;
    if (i >= BB * MEL) return;
    const int b = i / MEL, t = i - b * MEL;
    const int* cb = cum + b * LL;
    const int total = cb[LL - 1];
    int lo = 0, hi = LL;
    while (lo < hi) {
        const int mid = (lo + hi) >> 1;
        if (cb[mid] <= t) lo = mid + 1; else hi = mid;
    }
    int id = lo > LL - 1 ? LL - 1 : lo;
    idxm[i] = (t < total) ? id : -1;
}

// ---------------- gather: x fp32 -> expanded bf16 padded (bb0) -------------
__global__ void gather_kernel(const float* __restrict__ x, const int* __restrict__ idxm,
                              unsigned short* __restrict__ bb0) {
    const int i = blockIdx.x * 256 + threadIdx.x;   // i < BB*MEL*96
    const int row = i / 96;
    const int c4  = (i - row * 96) * 4;
    const int b = row >> 12, t = row & (MEL - 1);
    const int id = idxm[row];
    float4 v = make_float4(0.f, 0.f, 0.f, 0.f);
    if (id >= 0) v = *(const float4*)(x + ((size_t)b * LL + id) * CC + c4);
    uint2 pk;
    pk.x = (unsigned int)f2bf(v.x) | ((unsigned int)f2bf(v.y) << 16);
    pk.y = (unsigned int)f2bf(v.z) | ((unsigned int)f2bf(v.w) << 16);
    *(uint2*)(bb0 + ((size_t)b * (MEL + 2) + t + 1) * CC + c4) = pk;
}

// ---------------- be0 = bf16(bb0 + pv[row]) (energy conv input) ------------
__global__ void addp_kernel(const unsigned short* __restrict__ bb0,
                            const float* __restrict__ pv,
                            unsigned short* __restrict__ be0) {
    const int i = blockIdx.x * 256 + threadIdx.x;   // i < BB*MEL*48
    const int row = i / 48;
    const int c8  = (i - row * 48) * 8;
    const int b = row >> 12, t = row & (MEL - 1);
    const float p = pv[row];
    const size_t o = ((size_t)b * (MEL + 2) + t + 1) * CC + c8;
    const uint4 in = *(const uint4*)(bb0 + o);
    uint4 ot;
    const unsigned int w[4] = {in.x, in.y, in.z, in.w};
    unsigned int r[4];
    #pragma unroll
    for (int k = 0; k < 4; ++k) {
        const float lo = bf2f((unsigned short)w[k]) + p;
        const float hi = bf2f((unsigned short)(w[k] >> 16)) + p;
        r[k] = (unsigned int)f2bf(lo) | ((unsigned int)f2bf(hi) << 16);
    }
    ot.x = r[0]; ot.y = r[1]; ot.z = r[2]; ot.w = r[3];
    *(uint4*)(be0 + o) = ot;
}

// ---------------- out0 = x[idx] (fp32 exact) + pv + ev ---------------------
__global__ void final_kernel(const float* __restrict__ x, const int* __restrict__ idxm,
                             const float* __restrict__ pv, const float* __restrict__ ev,
                             float* __restrict__ out0) {
    const int i = blockIdx.x * 256 + threadIdx.x;   // i < BB*MEL*96
    const int row = i / 96;
    const int c4  = (i - row * 96) * 4;
    const int b = row >> 12;
    const int id = idxm[row];
    const float add = pv[row] + ev[row];
    float4 v = make_float4(0.f, 0.f, 0.f, 0.f);
    if (id >= 0) v = *(const float4*)(x + ((size_t)b * LL + id) * CC + c4);
    v.x += add; v.y += add; v.z += add; v.w += add;
    *(float4*)(out0 + (size_t)row * CC + c4) = v;
}

extern "C" void kernel_launch(void* const* d_in, const int* in_sizes, int n_in,
                              void* d_out, int out_size, void* d_ws, size_t ws_size,
                              hipStream_t stream) {
    const float* x = (const float*)d_in[0];
    const float* P[30];
    for (int i = 0; i < 30; ++i) P[i] = (const float*)d_in[1 + i];
    const int* dur = (const int*)d_in[31];
    float* out = (float*)d_out;

    char* ws = (char*)d_ws;
    const size_t WTT_ELEMS = (size_t)FF * KKT;            // 442368
    const size_t WTT_BYTES = WTT_ELEMS * 2;               // 884736
    unsigned short* wtt[6];
    for (int i = 0; i < 6; ++i) wtt[i] = (unsigned short*)(ws + i * WTT_BYTES);
    int* cum  = (int*)(ws + 5308416);
    int* idxm = (int*)(ws + 5341184);
    unsigned short* sb0 = (unsigned short*)(ws + 5603328);                 // [16][514][384]
    unsigned short* h1s = (unsigned short*)(ws + 11919360);                // [16][514][384]
    unsigned short* bb0 = (unsigned short*)(ws + 18235392);                // [16][4098][384]
    unsigned short* h1p = (unsigned short*)(ws + 68616192);                // [16][4098][384]
    unsigned short* be0 = (unsigned short*)(ws + 118996992);               // [16][4098][384]
    const size_t need = 169377792;
    if (ws_size < need)
        fprintf(stderr, "kernel_launch: ws too small: %zu < %zu\n", ws_size, need);

    const float *dp_w1=P[0], *dp_b1=P[1], *dp_g1=P[2], *dp_be1=P[3], *dp_w2=P[4],
                *dp_b2=P[5], *dp_g2=P[6], *dp_be2=P[7], *dp_wl=P[8], *dp_bl=P[9];
    const float *pp_w1=P[10], *pp_b1=P[11], *pp_g1=P[12], *pp_be1=P[13], *pp_w2=P[14],
                *pp_b2=P[15], *pp_g2=P[16], *pp_be2=P[17], *pp_wl=P[18], *pp_bl=P[19];
    const float *ep_w1=P[20], *ep_b1=P[21], *ep_g1=P[22], *ep_be1=P[23], *ep_w2=P[24],
                *ep_b2=P[25], *ep_g2=P[26], *ep_be2=P[27], *ep_wl=P[28], *ep_bl=P[29];

    const int wtg = (int)((WTT_ELEMS + 255) / 256);
    wtrans_kernel<<<wtg, 256, 0, stream>>>(dp_w1, wtt[0]);
    wtrans_kernel<<<wtg, 256, 0, stream>>>(dp_w2, wtt[1]);
    wtrans_kernel<<<wtg, 256, 0, stream>>>(pp_w1, wtt[2]);
    wtrans_kernel<<<wtg, 256, 0, stream>>>(pp_w2, wtt[3]);
    wtrans_kernel<<<wtg, 256, 0, stream>>>(ep_w1, wtt[4]);
    wtrans_kernel<<<wtg, 256, 0, stream>>>(ep_w2, wtt[5]);

    convert_x_kernel<<<(BB * LL * CC + 255) / 256, 256, 0, stream>>>(x, sb0);
    zpad_kernel<<<BB * 2, CC, 0, stream>>>(sb0, LL);
    zpad_kernel<<<BB * 2, CC, 0, stream>>>(h1s, LL);
    zpad_kernel<<<BB * 2, CC, 0, stream>>>(bb0, MEL);
    zpad_kernel<<<BB * 2, CC, 0, stream>>>(h1p, MEL);
    zpad_kernel<<<BB * 2, CC, 0, stream>>>(be0, MEL);

    cumsum_kernel<<<BB, LL, 0, stream>>>(dur, cum);
    idx_kernel<<<(BB * MEL + 255) / 256, 256, 0, stream>>>(cum, idxm);

    // duration predictor (T=512)
    conv_ln_kernel<LL, false><<<BB * LL / 128, 512, 0, stream>>>(
        sb0, wtt[0], dp_b1, dp_g1, dp_be1, h1s, nullptr, nullptr, nullptr);
    conv_ln_kernel<LL, true><<<BB * LL / 128, 512, 0, stream>>>(
        h1s, wtt[1], dp_b2, dp_g2, dp_be2, nullptr, dp_wl, dp_bl, out + O_DUR);

    // length regulate -> bb0 (bf16 padded)
    gather_kernel<<<BB * MEL * 96 / 256, 256, 0, stream>>>(x, idxm, bb0);

    // pitch predictor (T=4096)
    conv_ln_kernel<MEL, false><<<BB * MEL / 128, 512, 0, stream>>>(
        bb0, wtt[2], pp_b1, pp_g1, pp_be1, h1p, nullptr, nullptr, nullptr);
    conv_ln_kernel<MEL, true><<<BB * MEL / 128, 512, 0, stream>>>(
        h1p, wtt[3], pp_b2, pp_g2, pp_be2, nullptr, pp_wl, pp_bl, out + O_PIT);

    // energy input = bf16(expanded + pitches)
    addp_kernel<<<BB * MEL * 48 / 256, 256, 0, stream>>>(bb0, out + O_PIT, be0);

    // energy predictor (T=4096)
    conv_ln_kernel<MEL, false><<<BB * MEL / 128, 512, 0, stream>>>(
        be0, wtt[4], ep_b1, ep_g1, ep_be1, h1p, nullptr, nullptr, nullptr);
    conv_ln_kernel<MEL, true><<<BB * MEL / 128, 512, 0, stream>>>(
        h1p, wtt[5], ep_b2, ep_g2, ep_be2, nullptr, ep_wl, ep_bl, out + O_EN);

    // final: out = expanded(exact fp32) + pitches + energies
    final_kernel<<<BB * MEL * 96 / 256, 256, 0, stream>>>(
        x, idxm, out + O_PIT, out + O_EN, out + O_OUT);
}

// Round 6
// 431.709 us; speedup vs baseline: 1.7541x; 1.7541x over previous
//
#include <hip/hip_runtime.h>
#include <stdint.h>
#include <stdio.h>

#define BB   16
#define LL   512
#define CC   384
#define FF   384
#define KW   3
#define MEL  4096
#define KKT  (CC*KW)   // 1152

// output section offsets (fp32 elements)
#define O_OUT 0
#define N_OUT (BB*MEL*CC)          // 25165824
#define O_DUR (N_OUT)
#define O_PIT (O_DUR + BB*LL)
#define O_EN  (O_PIT + BB*MEL)

using bf16x8 = __attribute__((ext_vector_type(8))) short;
using f32x4  = __attribute__((ext_vector_type(4))) float;

__device__ __forceinline__ unsigned short f2bf(float v) {
    union { float f; unsigned int u; } cv; cv.f = v;
    unsigned int u = cv.u;
    u += 0x7FFFu + ((u >> 16) & 1u);   // RNE
    return (unsigned short)(u >> 16);
}
__device__ __forceinline__ float bf2f(unsigned short u) {
    union { unsigned int u; float f; } cv; cv.u = ((unsigned int)u) << 16; return cv.f;
}

__device__ __forceinline__ void gld_lds16(const unsigned short* gp, unsigned short* lp) {
    __builtin_amdgcn_global_load_lds(
        (const __attribute__((address_space(1))) unsigned int*)gp,
        (__attribute__((address_space(3))) unsigned int*)lp, 16, 0, 0);
}

// ------ weight transform: w[F][C][K] fp32 -> wt2 step-major chunk-major ----
// wt2[t][c][e]: t in 0..17 (K-step of 64), c = q*384+bn (q=chunk 0..7, bn=col),
// e = 0..7 shorts. Element = w[bn][ch][k] with kk = t*64+q*8+e, ch=kk%384, k=kk/384.
__global__ void wtrans_kernel(const float* __restrict__ w, unsigned short* __restrict__ wt2) {
    int i = blockIdx.x * 256 + threadIdx.x;
    if (i >= FF * KKT) return;
    const int t = i / 24576;
    const int r = i - t * 24576;
    const int c = r >> 3;
    const int e = r & 7;
    const int q = c / 384;
    const int bn = c - q * 384;
    const int kk = t * 64 + q * 8 + e;
    const int k = kk / CC;
    const int ch = kk - k * CC;
    wt2[i] = f2bf(w[(size_t)bn * KKT + ch * KW + k]);
}

// ---------------- x fp32 -> padded bf16 [B][L+2][C] ------------------------
__global__ void convert_x_kernel(const float* __restrict__ x, unsigned short* __restrict__ o) {
    int i = blockIdx.x * 256 + threadIdx.x;
    if (i >= BB * LL * CC) return;
    int b = i / (LL * CC);
    int r = i - b * (LL * CC);
    int t = r / CC;
    int c = r - t * CC;
    o[((size_t)b * (LL + 2) + t + 1) * CC + c] = f2bf(x[i]);
}

// ---------------- zero the two pad rows per batch --------------------------
__global__ void zpad_kernel(unsigned short* __restrict__ buf, int T) {
    int b = blockIdx.x >> 1;
    int w = blockIdx.x & 1;
    size_t row = (size_t)b * (T + 2) + (w ? (T + 1) : 0);
    buf[row * CC + threadIdx.x] = 0;
}

// ---------------- fused Conv(K=3)+bias+ReLU+LN [+Linear] -------------------
// Tile M=128 x N=384(all F), BK=64, NT=18 steps. 512 thr, 8 waves (2Mx4N).
// LDS: 2 buffers x 64KB. A: row-major 128B rows, XOR ca=q^(row&7) (G4 pattern,
// pre-swizzled coalesced source). B: chunk-major cells q*384+bn (0-conflict,
// coalesced via wt2 step-major layout). Schedule per step: vmcnt(8) -> barrier
// -> compute (48 MFMA) -> barrier -> stage(t+2) into the buffer just drained.
template<int T, bool FL>
__global__ __launch_bounds__(512)
void conv_ln_kernel(const unsigned short* __restrict__ inb,
                    const unsigned short* __restrict__ wt2,
                    const float* __restrict__ bias,
                    const float* __restrict__ g,
                    const float* __restrict__ be,
                    unsigned short* __restrict__ outb,
                    const float* __restrict__ wl,
                    const float* __restrict__ bl,
                    float* __restrict__ op) {
    // per buffer (shorts): A 8192 (16KB, 1024 cells) + B 24576 (48KB, 3072 cells)
    __shared__ __align__(16) unsigned short LDS[2][32768];

    constexpr int NT = KKT / 64;   // 18
    const int m0 = blockIdx.x * 128;
    const int b  = m0 / T;
    const int t0 = m0 - b * T;
    const int tid  = threadIdx.x;
    const int lane = tid & 63;
    const int wv   = tid >> 6;
    const int wr   = wv >> 2;          // 0..1 -> 64 rows
    const int wc   = wv & 3;           // 0..3 -> 96 cols

    // A staging sources (pre-swizzled within 128B row segments -> coalesced)
    const int rowS = tid >> 3;
    const int gch  = (tid & 7) ^ (rowS & 7);
    const unsigned short* srcA0 =
        inb + ((size_t)b * (T + 2) + t0 + rowS) * CC + gch * 8;
    const unsigned short* srcA1 =
        inb + ((size_t)b * (T + 2) + t0 + 64 + rowS) * CC + gch * 8;
    const unsigned short* srcB = wt2 + (size_t)tid * 8;   // + s*4096 + t*24576

    f32x4 acc[4][6] = {};

    auto stage = [&](int bi, int t) {
        const int offA = t * 64;
        gld_lds16(srcA0 + offA, &LDS[bi][(wv * 64) * 8]);
        gld_lds16(srcA1 + offA, &LDS[bi][(512 + wv * 64) * 8]);
        const size_t offB = (size_t)t * 24576;
        #pragma unroll
        for (int s = 0; s < 6; ++s)
            gld_lds16(srcB + offB + s * 4096,
                      &LDS[bi][8192 + (s * 512 + wv * 64) * 8]);
    };

    auto compute = [&](int bi) {
        const int q0 = lane >> 4;
        const int l15 = lane & 15;
        __builtin_amdgcn_s_setprio(1);
        #pragma unroll
        for (int kk = 0; kk < 2; ++kk) {
            bf16x8 af[4], bf[6];
            const int q = 4 * kk + q0;
            const int ca = q ^ (lane & 7);
            #pragma unroll
            for (int i = 0; i < 4; ++i) {
                const int ar = wr * 64 + i * 16 + l15;
                af[i] = *reinterpret_cast<const bf16x8*>(&LDS[bi][(ar * 8 + ca) * 8]);
            }
            #pragma unroll
            for (int j = 0; j < 6; ++j) {
                const int bn = wc * 96 + j * 16 + l15;
                bf[j] = *reinterpret_cast<const bf16x8*>(&LDS[bi][8192 + (q * 384 + bn) * 8]);
            }
            #pragma unroll
            for (int i = 0; i < 4; ++i)
                #pragma unroll
                for (int j = 0; j < 6; ++j)
                    acc[i][j] = __builtin_amdgcn_mfma_f32_16x16x32_bf16(
                        af[i], bf[j], acc[i][j], 0, 0, 0);
        }
        __builtin_amdgcn_s_setprio(0);
    };

    // depth-2 prologue
    stage(0, 0);
    stage(1, 1);

    #pragma unroll 2
    for (int t = 0; t < NT; ++t) {
        asm volatile("s_waitcnt vmcnt(8)" ::: "memory");  // tile t's 8 loads landed
        __builtin_amdgcn_s_barrier();                     // all waves' t-loads in
        asm volatile("" ::: "memory");
        compute(t & 1);
        asm volatile("" ::: "memory");
        __builtin_amdgcn_s_barrier();                     // buf[t&1] fully consumed
        int nt_ = t + 2; if (nt_ > NT - 1) nt_ = NT - 1;  // dup-stage tail
        stage(t & 1, nt_);
    }
    asm volatile("s_waitcnt vmcnt(0)" ::: "memory");      // drain dup stages
    __syncthreads();

    // ---------------- epilogue: bias + ReLU + LN [+ Linear] ----------------
    const int colb = wc * 96 + (lane & 15);
    float b6[6];
    #pragma unroll
    for (int j = 0; j < 6; ++j) b6[j] = bias[colb + j * 16];
    #pragma unroll
    for (int i = 0; i < 4; ++i)
        #pragma unroll
        for (int j = 0; j < 6; ++j)
            #pragma unroll
            for (int r = 0; r < 4; ++r) {
                float v = acc[i][j][r] + b6[j];
                acc[i][j][r] = v > 0.f ? v : 0.f;
            }

    // per-row partial sums (16-lane groups share a row)
    float S1[4][4], S2[4][4];
    #pragma unroll
    for (int i = 0; i < 4; ++i)
        #pragma unroll
        for (int r = 0; r < 4; ++r) {
            float s = 0.f, s2 = 0.f;
            #pragma unroll
            for (int j = 0; j < 6; ++j) { const float v = acc[i][j][r]; s += v; s2 += v * v; }
            #pragma unroll
            for (int m = 1; m <= 8; m <<= 1) { s += __shfl_xor(s, m); s2 += __shfl_xor(s2, m); }
            S1[i][r] = s; S2[i][r] = s2;
        }

    float2* red = (float2*)&LDS[0][0];     // 128 rows x 4 col-waves
    if ((lane & 15) == 0) {
        const int q = lane >> 4;
        #pragma unroll
        for (int i = 0; i < 4; ++i)
            #pragma unroll
            for (int r = 0; r < 4; ++r)
                red[(wr * 64 + i * 16 + q * 4 + r) * 4 + wc] = make_float2(S1[i][r], S2[i][r]);
    }
    __syncthreads();

    float g6[6], be6[6];
    #pragma unroll
    for (int j = 0; j < 6; ++j) { g6[j] = g[colb + j * 16]; be6[j] = be[colb + j * 16]; }

    if (!FL) {
        #pragma unroll
        for (int i = 0; i < 4; ++i)
            #pragma unroll
            for (int r = 0; r < 4; ++r) {
                const int row = wr * 64 + i * 16 + (lane >> 4) * 4 + r;
                const float2 p0 = red[row * 4 + 0], p1 = red[row * 4 + 1];
                const float2 p2 = red[row * 4 + 2], p3 = red[row * 4 + 3];
                const float S = p0.x + p1.x + p2.x + p3.x;
                const float Q = p0.y + p1.y + p2.y + p3.y;
                const float mu = S * (1.f / 384.f);
                const float rs = rsqrtf(Q * (1.f / 384.f) - mu * mu + 1e-5f);
                unsigned short* qp = outb + ((size_t)b * (T + 2) + t0 + row + 1) * CC + colb;
                #pragma unroll
                for (int j = 0; j < 6; ++j)
                    qp[j * 16] = f2bf((acc[i][j][r] - mu) * rs * g6[j] + be6[j]);
            }
    } else {
        float wl6[6];
        #pragma unroll
        for (int j = 0; j < 6; ++j) wl6[j] = wl[colb + j * 16];
        float* redl = (float*)&LDS[1][0];
        #pragma unroll
        for (int i = 0; i < 4; ++i)
            #pragma unroll
            for (int r = 0; r < 4; ++r) {
                const int row = wr * 64 + i * 16 + (lane >> 4) * 4 + r;
                const float2 p0 = red[row * 4 + 0], p1 = red[row * 4 + 1];
                const float2 p2 = red[row * 4 + 2], p3 = red[row * 4 + 3];
                const float S = p0.x + p1.x + p2.x + p3.x;
                const float Q = p0.y + p1.y + p2.y + p3.y;
                const float mu = S * (1.f / 384.f);
                const float rs = rsqrtf(Q * (1.f / 384.f) - mu * mu + 1e-5f);
                float sl = 0.f;
                #pragma unroll
                for (int j = 0; j < 6; ++j)
                    sl += ((acc[i][j][r] - mu) * rs * g6[j] + be6[j]) * wl6[j];
                #pragma unroll
                for (int m = 1; m <= 8; m <<= 1) sl += __shfl_xor(sl, m);
                if ((lane & 15) == 0) redl[row * 4 + wc] = sl;
            }
        __syncthreads();
        if (tid < 128)
            op[m0 + tid] = redl[tid * 4] + redl[tid * 4 + 1] +
                           redl[tid * 4 + 2] + redl[tid * 4 + 3] + bl[0];
    }
}

// ---------------- cumsum of dur per batch ----------------------------------
__global__ void cumsum_kernel(const int* __restrict__ dur, int* __restrict__ cum) {
    __shared__ int s[LL];
    const int b = blockIdx.x, t = threadIdx.x;
    s[t] = dur[b * LL + t];
    __syncthreads();
    for (int off = 1; off < LL; off <<= 1) {
        int v = (t >= off) ? s[t - off] : 0;
        __syncthreads();
        s[t] += v;
        __syncthreads();
    }
    cum[b * LL + t] = s[t];
}

// ---------------- frame -> phoneme index (binary search), -1 if masked -----
__global__ void idx_kernel(const int* __restrict__ cum, int* __restrict__ idxm) {
    const int i = blockIdx.x * 256 + threadIdx.x;
    if (i >= BB * MEL) return;
    const int b = i / MEL, t = i - b * MEL;
    const int* cb = cum + b * LL;
    const int total = cb[LL - 1];
    int lo = 0, hi = LL;
    while (lo < hi) {
        const int mid = (lo + hi) >> 1;
        if (cb[mid] <= t) lo = mid + 1; else hi = mid;
    }
    int id = lo > LL - 1 ? LL - 1 : lo;
    idxm[i] = (t < total) ? id : -1;
}

// ---------------- gather: x fp32 -> expanded bf16 padded (bb0) -------------
__global__ void gather_kernel(const float* __restrict__ x, const int* __restrict__ idxm,
                              unsigned short* __restrict__ bb0) {
    const int i = blockIdx.x * 256 + threadIdx.x;   // i < BB*MEL*96
    const int row = i / 96;
    const int c4  = (i - row * 96) * 4;
    const int b = row >> 12, t = row & (MEL - 1);
    const int id = idxm[row];
    float4 v = make_float4(0.f, 0.f, 0.f, 0.f);
    if (id >= 0) v = *(const float4*)(x + ((size_t)b * LL + id) * CC + c4);
    uint2 pk;
    pk.x = (unsigned int)f2bf(v.x) | ((unsigned int)f2bf(v.y) << 16);
    pk.y = (unsigned int)f2bf(v.z) | ((unsigned int)f2bf(v.w) << 16);
    *(uint2*)(bb0 + ((size_t)b * (MEL + 2) + t + 1) * CC + c4) = pk;
}

// ---------------- be0 = bf16(bb0 + pv[row]) (energy conv input) ------------
__global__ void addp_kernel(const unsigned short* __restrict__ bb0,
                            const float* __restrict__ pv,
                            unsigned short* __restrict__ be0) {
    const int i = blockIdx.x * 256 + threadIdx.x;   // i < BB*MEL*48
    const int row = i / 48;
    const int c8  = (i - row * 48) * 8;
    const int b = row >> 12, t = row & (MEL - 1);
    const float p = pv[row];
    const size_t o = ((size_t)b * (MEL + 2) + t + 1) * CC + c8;
    const uint4 in = *(const uint4*)(bb0 + o);
    uint4 ot;
    const unsigned int w[4] = {in.x, in.y, in.z, in.w};
    unsigned int r[4];
    #pragma unroll
    for (int k = 0; k < 4; ++k) {
        const float lo = bf2f((unsigned short)w[k]) + p;
        const float hi = bf2f((unsigned short)(w[k] >> 16)) + p;
        r[k] = (unsigned int)f2bf(lo) | ((unsigned int)f2bf(hi) << 16);
    }
    ot.x = r[0]; ot.y = r[1]; ot.z = r[2]; ot.w = r[3];
    *(uint4*)(be0 + o) = ot;
}

// ---------------- out0 = x[idx] (fp32 exact) + pv + ev ---------------------
__global__ void final_kernel(const float* __restrict__ x, const int* __restrict__ idxm,
                             const float* __restrict__ pv, const float* __restrict__ ev,
                             float* __restrict__ out0) {
    const int i = blockIdx.x * 256 + threadIdx.x;   // i < BB*MEL*96
    const int row = i / 96;
    const int c4  = (i - row * 96) * 4;
    const int b = row >> 12;
    const int id = idxm[row];
    const float add = pv[row] + ev[row];
    float4 v = make_float4(0.f, 0.f, 0.f, 0.f);
    if (id >= 0) v = *(const float4*)(x + ((size_t)b * LL + id) * CC + c4);
    v.x += add; v.y += add; v.z += add; v.w += add;
    *(float4*)(out0 + (size_t)row * CC + c4) = v;
}

extern "C" void kernel_launch(void* const* d_in, const int* in_sizes, int n_in,
                              void* d_out, int out_size, void* d_ws, size_t ws_size,
                              hipStream_t stream) {
    const float* x = (const float*)d_in[0];
    const float* P[30];
    for (int i = 0; i < 30; ++i) P[i] = (const float*)d_in[1 + i];
    const int* dur = (const int*)d_in[31];
    float* out = (float*)d_out;

    char* ws = (char*)d_ws;
    const size_t WTT_ELEMS = (size_t)FF * KKT;            // 442368
    const size_t WTT_BYTES = WTT_ELEMS * 2;               // 884736
    unsigned short* wtt[6];
    for (int i = 0; i < 6; ++i) wtt[i] = (unsigned short*)(ws + i * WTT_BYTES);
    int* cum  = (int*)(ws + 5308416);
    int* idxm = (int*)(ws + 5341184);
    unsigned short* sb0 = (unsigned short*)(ws + 5603328);                 // [16][514][384]
    unsigned short* h1s = (unsigned short*)(ws + 11919360);                // [16][514][384]
    unsigned short* bb0 = (unsigned short*)(ws + 18235392);                // [16][4098][384]
    unsigned short* h1p = (unsigned short*)(ws + 68616192);                // [16][4098][384]
    unsigned short* be0 = (unsigned short*)(ws + 118996992);               // [16][4098][384]
    const size_t need = 169377792;
    if (ws_size < need)
        fprintf(stderr, "kernel_launch: ws too small: %zu < %zu\n", ws_size, need);

    const float *dp_w1=P[0], *dp_b1=P[1], *dp_g1=P[2], *dp_be1=P[3], *dp_w2=P[4],
                *dp_b2=P[5], *dp_g2=P[6], *dp_be2=P[7], *dp_wl=P[8], *dp_bl=P[9];
    const float *pp_w1=P[10], *pp_b1=P[11], *pp_g1=P[12], *pp_be1=P[13], *pp_w2=P[14],
                *pp_b2=P[15], *pp_g2=P[16], *pp_be2=P[17], *pp_wl=P[18], *pp_bl=P[19];
    const float *ep_w1=P[20], *ep_b1=P[21], *ep_g1=P[22], *ep_be1=P[23], *ep_w2=P[24],
                *ep_b2=P[25], *ep_g2=P[26], *ep_be2=P[27], *ep_wl=P[28], *ep_bl=P[29];

    const int wtg = (int)((WTT_ELEMS + 255) / 256);
    wtrans_kernel<<<wtg, 256, 0, stream>>>(dp_w1, wtt[0]);
    wtrans_kernel<<<wtg, 256, 0, stream>>>(dp_w2, wtt[1]);
    wtrans_kernel<<<wtg, 256, 0, stream>>>(pp_w1, wtt[2]);
    wtrans_kernel<<<wtg, 256, 0, stream>>>(pp_w2, wtt[3]);
    wtrans_kernel<<<wtg, 256, 0, stream>>>(ep_w1, wtt[4]);
    wtrans_kernel<<<wtg, 256, 0, stream>>>(ep_w2, wtt[5]);

    convert_x_kernel<<<(BB * LL * CC + 255) / 256, 256, 0, stream>>>(x, sb0);
    zpad_kernel<<<BB * 2, CC, 0, stream>>>(sb0, LL);
    zpad_kernel<<<BB * 2, CC, 0, stream>>>(h1s, LL);
    zpad_kernel<<<BB * 2, CC, 0, stream>>>(bb0, MEL);
    zpad_kernel<<<BB * 2, CC, 0, stream>>>(h1p, MEL);
    zpad_kernel<<<BB * 2, CC, 0, stream>>>(be0, MEL);

    cumsum_kernel<<<BB, LL, 0, stream>>>(dur, cum);
    idx_kernel<<<(BB * MEL + 255) / 256, 256, 0, stream>>>(cum, idxm);

    // duration predictor (T=512)
    conv_ln_kernel<LL, false><<<BB * LL / 128, 512, 0, stream>>>(
        sb0, wtt[0], dp_b1, dp_g1, dp_be1, h1s, nullptr, nullptr, nullptr);
    conv_ln_kernel<LL, true><<<BB * LL / 128, 512, 0, stream>>>(
        h1s, wtt[1], dp_b2, dp_g2, dp_be2, nullptr, dp_wl, dp_bl, out + O_DUR);

    // length regulate -> bb0 (bf16 padded)
    gather_kernel<<<BB * MEL * 96 / 256, 256, 0, stream>>>(x, idxm, bb0);

    // pitch predictor (T=4096)
    conv_ln_kernel<MEL, false><<<BB * MEL / 128, 512, 0, stream>>>(
        bb0, wtt[2], pp_b1, pp_g1, pp_be1, h1p, nullptr, nullptr, nullptr);
    conv_ln_kernel<MEL, true><<<BB * MEL / 128, 512, 0, stream>>>(
        h1p, wtt[3], pp_b2, pp_g2, pp_be2, nullptr, pp_wl, pp_bl, out + O_PIT);

    // energy input = bf16(expanded + pitches)
    addp_kernel<<<BB * MEL * 48 / 256, 256, 0, stream>>>(bb0, out + O_PIT, be0);

    // energy predictor (T=4096)
    conv_ln_kernel<MEL, false><<<BB * MEL / 128, 512, 0, stream>>>(
        be0, wtt[4], ep_b1, ep_g1, ep_be1, h1p, nullptr, nullptr, nullptr);
    conv_ln_kernel<MEL, true><<<BB * MEL / 128, 512, 0, stream>>>(
        h1p, wtt[5], ep_b2, ep_g2, ep_be2, nullptr, ep_wl, ep_bl, out + O_EN);

    // final: out = expanded(exact fp32) + pitches + energies
    final_kernel<<<BB * MEL * 96 / 256, 256, 0, stream>>>(
        x, idxm, out + O_PIT, out + O_EN, out + O_OUT);
}